// Round 18
// baseline (61.795 us; speedup 1.0000x reference)
//
#include <hip/hip_runtime.h>
#include <hip/hip_bf16.h>

typedef __attribute__((ext_vector_type(8))) short bf16x8;
typedef __attribute__((ext_vector_type(16))) float f32x16;

#define CDIM 192
#define NTOK 196
#define LTOT 392
#define NBE 64

__device__ __forceinline__ ushort f2bf(float f) {
  uint u = __float_as_uint(f);
  u = (u + 0x7FFFu + ((u >> 16) & 1u)) >> 16;
  return (ushort)u;
}
__device__ __forceinline__ float bf2f(ushort h) {
  return __uint_as_float(((uint)h) << 16);
}
__device__ __forceinline__ uint pk2(float lo, float hi) {
  __hip_bfloat162 t = __float22bfloat162_rn(float2{lo, hi});
  uint r;
  __builtin_memcpy(&r, &t, 4);
  return r;
}
__device__ __forceinline__ float wave_reduce(float a) {
#pragma unroll
  for (int off = 32; off > 0; off >>= 1) a += __shfl_xor(a, off);
  return a;
}
// Raw barrier: LDS-visibility only (lgkmcnt); does NOT drain in-flight global
// loads (unlike __syncthreads' vmcnt(0) drain) — keeps prefetches pipelined.
__device__ __forceinline__ void barL() {
  asm volatile("s_waitcnt lgkmcnt(0)" ::: "memory");
  __builtin_amdgcn_s_barrier();
  __builtin_amdgcn_sched_barrier(0);
}

// ---------------- prep: fold BN (bf16 weights), u3/u4/K via wave-reductions ---
__global__ __launch_bounds__(256) void prep_kernel(
    const float* __restrict__ w1, const float* __restrict__ b1, const float* __restrict__ g1,
    const float* __restrict__ be1, const float* __restrict__ m1, const float* __restrict__ v1,
    const float* __restrict__ w2, const float* __restrict__ b2, const float* __restrict__ g2,
    const float* __restrict__ be2, const float* __restrict__ m2, const float* __restrict__ v2,
    const float* __restrict__ w3, const float* __restrict__ b3,
    const float* __restrict__ w4, const float* __restrict__ b4,
    const float* __restrict__ w5, const float* __restrict__ b5,
    ushort* __restrict__ w1b, ushort* __restrict__ w2b,
    float* __restrict__ u3, float* __restrict__ u4, float* __restrict__ cvecs,
    float* __restrict__ Kc) {
  const int bid = blockIdx.x;
  const int wid = threadIdx.x >> 6, lane = threadIdx.x & 63;
  if (bid < NBE) {
    for (int i = bid * 256 + threadIdx.x; i < 74112; i += NBE * 256) {
      if (i < 36864) {
        int o = i / CDIM;
        float inv = g1[o] * rsqrtf(v1[o] + 1e-5f);
        w1b[i] = f2bf(w1[i] * inv);
      } else if (i < 73728) {
        int j = i - 36864; int o = j / CDIM;
        float inv = g2[o] * rsqrtf(v2[o] + 1e-5f);
        w2b[j] = f2bf(w2[j] * inv);
      } else {
        int k = i - 73728; int h = k / CDIM, o = k % CDIM;
        const float* bb = h ? b2 : b1; const float* gg = h ? g2 : g1;
        const float* bee = h ? be2 : be1;
        const float* mm = h ? m2 : m1; const float* vv = h ? v2 : v1;
        float inv = gg[o] * rsqrtf(vv[o] + 1e-5f);
        cvecs[k] = (bb[o] - mm[o]) * inv + bee[o];
      }
    }
  } else if (bid < NBE + 48) {            // u3: wave per output j
    int j = (bid - NBE) * 4 + wid;
    float a = 0.f;
    for (int c = lane; c < CDIM; c += 64) a += w5[c] * w3[c * CDIM + j];
    a = wave_reduce(a);
    if (lane == 0) u3[j] = a;
  } else if (bid < NBE + 48 + 98) {       // u4: wave per output j
    int j = (bid - NBE - 48) * 4 + wid;
    float a = 0.f;
    for (int o = lane; o < 784; o += 64)
      a += w5[CDIM + o] * (w4[o * 784 + j] + w4[o * 784 + j + LTOT]);
    a = wave_reduce(a);
    if (lane == 0) u4[j] = a;
  } else {                                // Kc: single wave
    if (wid == 0) {
      float a = 0.f;
      for (int i = lane; i < CDIM + 784; i += 64)
        a += (i < CDIM) ? w5[i] * b3[i] : w5[i] * b4[i - CDIM];
      a = wave_reduce(a);
      if (lane == 0) Kc[0] = a + b5[0];
    }
  }
}

// --- fully fused: phi (32x32 MFMA, in LDS) + s + W + out.  1 block/b, 12 waves.
// LDS: Wl[392] | phiL[392*192 bf16, swz ^(l&7)<<4] | u4s[408] | csL[384] | sA[2][192]
#define OFF_WL 0
#define OFF_PHIL 1568
#define OFF_U4S (OFF_PHIL + 150528)
#define OFF_CSL (OFF_U4S + 1632)
#define OFF_SA (OFF_CSL + 1536)
#define SMEM_BYTES (OFF_SA + 1536)

extern __shared__ char smem[];

__global__ __launch_bounds__(768, 1) void fused_kernel(
    const float* __restrict__ x, const float* __restrict__ y,
    const ushort* __restrict__ w1b, const ushort* __restrict__ w2b,
    const float* __restrict__ cvecs, const float* __restrict__ u4,
    const float* __restrict__ u3, const float* __restrict__ Kc,
    float* __restrict__ out) {
  const int b = blockIdx.x;
  float* Wl = (float*)(smem + OFF_WL);
  char* phiB = smem + OFF_PHIL;
  float* u4s = (float*)(smem + OFF_U4S);
  float* csL = (float*)(smem + OFF_CSL);
  float* sA = (float*)(smem + OFF_SA);    // [2][192]
  const int tid = threadIdx.x;
  for (int i = tid; i < 408; i += 768) u4s[i] = (i < LTOT) ? u4[i] : 0.f;
  for (int i = tid; i < 384; i += 768) csL[i] = cvecs[i];

  const int w = tid >> 6, lane = tid & 63;
  const int cw = w % 6, lg = w / 6;       // wave owns c-tile cw (32 ch), l-group lg
  const int cbase = cw * 32;
  const int cl32 = lane & 31, hi = lane >> 5;
  const int c = cbase + cl32;             // this lane's channel (epi/B-frag)

  bf16x8 bfr[12];                         // current half's B-frags (K=192 = 12x16)
#pragma unroll
  for (int kk = 0; kk < 12; kk++)
    bfr[kk] = *(const bf16x8*)(w1b + (size_t)c * CDIM + kk * 16 + hi * 8);

  const float4* xb4 = (const float4*)(x + (size_t)b * NTOK * CDIM);
  const float4* yb4 = (const float4*)(y + (size_t)b * NTOK * CDIM);
  float4 pfA[6], pfB[7];
  float sp = 0.f;

  // chunkA = rows 0..95 (4608 f4, exact); chunkB = rows 96..195 (4800 f4, mask)
  auto loadA = [&](const float4* s4) {
#pragma unroll
    for (int p = 0; p < 6; p++) pfA[p] = s4[p * 768 + tid];
  };
  auto loadB = [&](const float4* s4) {
#pragma unroll
    for (int p = 0; p < 7; p++) {
      const int fi = p * 768 + tid;
      pfB[p] = (fi < 4800) ? s4[4608 + fi] : float4{0.f, 0.f, 0.f, 0.f};
    }
  };
  auto stageA = [&](int h) {
#pragma unroll
    for (int p = 0; p < 6; p++) {
      const int fi = p * 768 + tid;
      const int l = h * NTOK + fi / 48, c4 = fi % 48;
      uint2 wv;
      wv.x = pk2(pfA[p].x, pfA[p].y);
      wv.y = pk2(pfA[p].z, pfA[p].w);
      uint addr = (uint)(l * 384 + c4 * 8) ^ (uint)((l & 7) << 4);
      *(uint2*)(phiB + addr) = wv;
    }
  };
  auto stageB = [&](int h) {
#pragma unroll
    for (int p = 0; p < 7; p++) {
      const int fi = p * 768 + tid;
      if (fi < 4800) {
        const int l = h * NTOK + 96 + fi / 48, c4 = fi % 48;
        uint2 wv;
        wv.x = pk2(pfB[p].x, pfB[p].y);
        wv.y = pk2(pfB[p].z, pfB[p].w);
        uint addr = (uint)(l * 384 + c4 * 8) ^ (uint)((l & 7) << 4);
        *(uint2*)(phiB + addr) = wv;
      }
    }
  };

  // one 32x32 tile: MFMA into acc (A from phiL rows l0..l0+31 of half h)
  auto tileMFMA = [&](int h, int l0) -> f32x16 {
    f32x16 acc;
#pragma unroll
    for (int e = 0; e < 16; e++) acc[e] = 0.f;
    const int l = h * NTOK + l0 + cl32;
    const uint swz = (uint)((l & 7) << 4);
#pragma unroll
    for (int kk = 0; kk < 12; kk++) {
      uint ad = (uint)(l * 384 + kk * 32 + hi * 16) ^ swz;
      bf16x8 af = *(const bf16x8*)(phiB + ad);
      acc = __builtin_amdgcn_mfma_f32_32x32x16_bf16(af, bfr[kk], acc, 0, 0, 0);
    }
    return acc;
  };
  // epi: relu+bias -> phi overwrites A rows; s partial. ovl: only rows >= 192.
  auto tileEPI = [&](int h, int l0, const f32x16& acc, float csr, bool ovl) {
#pragma unroll
    for (int e = 0; e < 16; e++) {
      const int rl = (e & 3) + 8 * (e >> 2) + 4 * hi;
      const int row = l0 + rl;
      if (!ovl || row >= 192) {
        const float v = fmaxf(acc[e] + csr, 0.f);
        const int l = h * NTOK + row;
        uint addr = (uint)(l * 384 + c * 2) ^ (uint)((l & 7) << 4);
        *(ushort*)(phiB + addr) = f2bf(v);
        sp += u4s[l] * v;
      }
    }
  };
  auto chunkCompute = [&](int h, int cb, float csr) {
    // cb=0: tiles {0,32,64}; cb=1: tiles {96,128,160,164(ovl)}
    const int l0s[2][4] = {{0, 32, 64, -1}, {96, 128, 160, 164}};
    const int nt = cb ? 4 : 3;
    f32x16 a0, a1;
    const int t0 = lg, t1 = lg + 2;
    if (t0 < nt) a0 = tileMFMA(h, l0s[cb][t0]);
    if (t1 < nt) a1 = tileMFMA(h, l0s[cb][t1]);
    barL();                               // all A reads drained before overwrite
    if (t0 < nt) tileEPI(h, l0s[cb][t0], a0, csr, cb && l0s[cb][t0] == 164);
    if (t1 < nt) tileEPI(h, l0s[cb][t1], a1, csr, cb && l0s[cb][t1] == 164);
  };

  loadA(xb4);
  loadB(xb4);
  stageA(0);
  loadA(yb4);                             // y chunkA in flight across barriers
  barL();
  const float csr0 = csL[c], csr1 = csL[CDIM + c];
  chunkCompute(0, 0, csr0);
  stageB(0);
  loadB(yb4);                             // y chunkB in flight
  barL();
  chunkCompute(0, 1, csr0);
#pragma unroll
  for (int kk = 0; kk < 12; kk++)         // switch to half-1 weights (L2-hot)
    bfr[kk] = *(const bf16x8*)(w2b + (size_t)c * CDIM + kk * 16 + hi * 8);
  stageA(1);
  barL();
  chunkCompute(1, 0, csr1);
  stageB(1);
  barL();
  chunkCompute(1, 1, csr1);

  // s reduction: lane holds column c over its rows; fold hi via xor 32
  sp += __shfl_xor(sp, 32);
  if (hi == 0) sA[lg * CDIM + c] = sp;
  barL();
  for (int i = tid; i < CDIM; i += 768) sA[i] = u3[i] + sA[i] + sA[CDIM + i];
  barL();

  // W phase: 16 rows x 4 kgrp per wave (bank-balanced b128 reads), W -> Wl
  {
    const float Kv = Kc[0];
    const int lrow = lane & 15, kgrp = lane >> 4;
#pragma unroll
    for (int p = 0; p < 3; p++) {
      const int row = p * 192 + w * 16 + lrow;
      float acc = 0.f;
      if (row < LTOT) {
#pragma unroll
        for (int kk = 0; kk < 6; kk++) {
          const int c0 = kk * 32 + kgrp * 8;
          uint addr = (uint)(row * 384 + c0 * 2) ^ (uint)((row & 7) << 4);
          const uint4 pv = *(const uint4*)(phiB + addr);
          const float4 cfa = *(const float4*)&sA[c0];
          const float4 cfb = *(const float4*)&sA[c0 + 4];
          acc += cfa.x * bf2f((ushort)pv.x) + cfa.y * bf2f((ushort)(pv.x >> 16))
               + cfa.z * bf2f((ushort)pv.y) + cfa.w * bf2f((ushort)(pv.y >> 16))
               + cfb.x * bf2f((ushort)pv.z) + cfb.y * bf2f((ushort)(pv.z >> 16))
               + cfb.z * bf2f((ushort)pv.w) + cfb.w * bf2f((ushort)(pv.w >> 16));
        }
      }
      acc += __shfl_xor(acc, 16);
      acc += __shfl_xor(acc, 32);
      if (kgrp == 0 && row < LTOT) Wl[row] = acc + Kv;
    }
  }
  barL();  // Wl visible; phiL reads done -> tiles may overwrite

  // out phase: BARRIER-FREE. wave owns c-strip [w*16, w*16+16); private slab
  // [16][68] f32 over dead phiL. 4 slabs of 64 n. out[b,c,n]=x*Wx+y*Wy.
  {
    float* tf = (float*)(phiB + w * 4352);    // 16*68*4 = 4352 B per wave
    const int cb16 = w * 16;
    const float* xb = x + (size_t)b * NTOK * CDIM;
    const float* yb = y + (size_t)b * NTOK * CDIM;
    const int nrow = lane >> 2, cq = lane & 3;     // combine mapping
    const int scl = lane >> 2, sq = lane & 3;      // store mapping
    for (int s0 = 0; s0 < 4; s0++) {
      const int n0 = s0 * 64;
#pragma unroll
      for (int i2 = 0; i2 < 4; i2++) {
        const int n = n0 + i2 * 16 + nrow;
        if (n < NTOK) {
          const size_t xi = (size_t)n * CDIM + cb16 + cq * 4;
          const float4 xv = *(const float4*)&xb[xi];
          const float4 yv = *(const float4*)&yb[xi];
          const float wx = Wl[n], wy = Wl[NTOK + n];
          const int dn = n - n0;
          tf[(cq * 4 + 0) * 68 + dn] = xv.x * wx + yv.x * wy;
          tf[(cq * 4 + 1) * 68 + dn] = xv.y * wx + yv.y * wy;
          tf[(cq * 4 + 2) * 68 + dn] = xv.z * wx + yv.z * wy;
          tf[(cq * 4 + 3) * 68 + dn] = xv.w * wx + yv.w * wy;
        }
      }
      asm volatile("s_waitcnt lgkmcnt(0)" ::: "memory");  // own slab writes done
#pragma unroll
      for (int i2 = 0; i2 < 4; i2++) {
        const int n = n0 + i2 * 16 + sq * 4;
        if (n < NTOK) {
          const float4 o = *(const float4*)&tf[scl * 68 + (n - n0)];
          *(float4*)&out[((size_t)b * CDIM + cb16 + scl) * NTOK + n] = o;
        }
      }
    }
  }
}

extern "C" void kernel_launch(void* const* d_in, const int* in_sizes, int n_in,
                              void* d_out, int out_size, void* d_ws, size_t ws_size,
                              hipStream_t stream) {
  const float* x   = (const float*)d_in[0];
  const float* y   = (const float*)d_in[1];
  const float* w1  = (const float*)d_in[2];
  const float* b1  = (const float*)d_in[3];
  const float* g1  = (const float*)d_in[4];
  const float* be1 = (const float*)d_in[5];
  const float* m1  = (const float*)d_in[6];
  const float* v1  = (const float*)d_in[7];
  const float* w2  = (const float*)d_in[8];
  const float* b2  = (const float*)d_in[9];
  const float* g2  = (const float*)d_in[10];
  const float* be2 = (const float*)d_in[11];
  const float* m2  = (const float*)d_in[12];
  const float* v2  = (const float*)d_in[13];
  const float* w3  = (const float*)d_in[14];
  const float* b3  = (const float*)d_in[15];
  const float* w4  = (const float*)d_in[16];
  const float* b4  = (const float*)d_in[17];
  const float* w5  = (const float*)d_in[18];
  const float* b5  = (const float*)d_in[19];
  float* out = (float*)d_out;

  char* ws = (char*)d_ws;
  ushort* w1b  = (ushort*)ws;             // 73728 B
  ushort* w2b  = (ushort*)(ws + 73728);   // 73728 B
  float* fbase = (float*)(ws + 147456);
  float* u3    = fbase;                   // 192
  float* u4    = fbase + 192;             // 392
  float* cvecs = fbase + 584;             // 384 (c1|c2)
  float* Kc    = fbase + 968;             // 1

  prep_kernel<<<211, 256, 0, stream>>>(w1, b1, g1, be1, m1, v1,
                                       w2, b2, g2, be2, m2, v2,
                                       w3, b3, w4, b4, w5, b5,
                                       w1b, w2b, u3, u4, cvecs, Kc);
  fused_kernel<<<256, 768, SMEM_BYTES, stream>>>(x, y, w1b, w2b, cvecs, u4,
                                                 u3, Kc, out);
}

// Round 20
// 61.641 us; speedup vs baseline: 1.0025x; 1.0025x over previous
//
#include <hip/hip_runtime.h>
#include <hip/hip_bf16.h>

typedef __attribute__((ext_vector_type(8))) short bf16x8;
typedef __attribute__((ext_vector_type(16))) float f32x16;

#define CDIM 192
#define NTOK 196
#define LTOT 392
#define NBE 64

__device__ __forceinline__ ushort f2bf(float f) {
  uint u = __float_as_uint(f);
  u = (u + 0x7FFFu + ((u >> 16) & 1u)) >> 16;
  return (ushort)u;
}
__device__ __forceinline__ float bf2f(ushort h) {
  return __uint_as_float(((uint)h) << 16);
}
__device__ __forceinline__ uint pk2(float lo, float hi) {
  __hip_bfloat162 t = __float22bfloat162_rn(float2{lo, hi});
  uint r;
  __builtin_memcpy(&r, &t, 4);
  return r;
}
__device__ __forceinline__ float wave_reduce(float a) {
#pragma unroll
  for (int off = 32; off > 0; off >>= 1) a += __shfl_xor(a, off);
  return a;
}
// Raw barrier: LDS-visibility only (lgkmcnt); does NOT drain in-flight global
// loads (unlike __syncthreads' vmcnt(0) drain) — keeps prefetches pipelined.
__device__ __forceinline__ void barL() {
  asm volatile("s_waitcnt lgkmcnt(0)" ::: "memory");
  __builtin_amdgcn_s_barrier();
  __builtin_amdgcn_sched_barrier(0);
}

// ---------------- prep: fold BN (bf16 weights), u3/u4/K via wave-reductions ---
__global__ __launch_bounds__(256) void prep_kernel(
    const float* __restrict__ w1, const float* __restrict__ b1, const float* __restrict__ g1,
    const float* __restrict__ be1, const float* __restrict__ m1, const float* __restrict__ v1,
    const float* __restrict__ w2, const float* __restrict__ b2, const float* __restrict__ g2,
    const float* __restrict__ be2, const float* __restrict__ m2, const float* __restrict__ v2,
    const float* __restrict__ w3, const float* __restrict__ b3,
    const float* __restrict__ w4, const float* __restrict__ b4,
    const float* __restrict__ w5, const float* __restrict__ b5,
    ushort* __restrict__ w1b, ushort* __restrict__ w2b,
    float* __restrict__ u3, float* __restrict__ u4, float* __restrict__ cvecs,
    float* __restrict__ Kc) {
  const int bid = blockIdx.x;
  const int wid = threadIdx.x >> 6, lane = threadIdx.x & 63;
  if (bid < NBE) {
    for (int i = bid * 256 + threadIdx.x; i < 74112; i += NBE * 256) {
      if (i < 36864) {
        int o = i / CDIM;
        float inv = g1[o] * rsqrtf(v1[o] + 1e-5f);
        w1b[i] = f2bf(w1[i] * inv);
      } else if (i < 73728) {
        int j = i - 36864; int o = j / CDIM;
        float inv = g2[o] * rsqrtf(v2[o] + 1e-5f);
        w2b[j] = f2bf(w2[j] * inv);
      } else {
        int k = i - 73728; int h = k / CDIM, o = k % CDIM;
        const float* bb = h ? b2 : b1; const float* gg = h ? g2 : g1;
        const float* bee = h ? be2 : be1;
        const float* mm = h ? m2 : m1; const float* vv = h ? v2 : v1;
        float inv = gg[o] * rsqrtf(vv[o] + 1e-5f);
        cvecs[k] = (bb[o] - mm[o]) * inv + bee[o];
      }
    }
  } else if (bid < NBE + 48) {            // u3: wave per output j
    int j = (bid - NBE) * 4 + wid;
    float a = 0.f;
    for (int c = lane; c < CDIM; c += 64) a += w5[c] * w3[c * CDIM + j];
    a = wave_reduce(a);
    if (lane == 0) u3[j] = a;
  } else if (bid < NBE + 48 + 98) {       // u4: wave per output j
    int j = (bid - NBE - 48) * 4 + wid;
    float a = 0.f;
    for (int o = lane; o < 784; o += 64)
      a += w5[CDIM + o] * (w4[o * 784 + j] + w4[o * 784 + j + LTOT]);
    a = wave_reduce(a);
    if (lane == 0) u4[j] = a;
  } else {                                // Kc: single wave
    if (wid == 0) {
      float a = 0.f;
      for (int i = lane; i < CDIM + 784; i += 64)
        a += (i < CDIM) ? w5[i] * b3[i] : w5[i] * b4[i - CDIM];
      a = wave_reduce(a);
      if (lane == 0) Kc[0] = a + b5[0];
    }
  }
}

// --- fully fused: phi (32x32 MFMA, in LDS) + s + W + out.  1 block/b, 12 waves.
// LDS: Wl[392] | phiL[392*192 bf16, swz ^(l&7)<<4] | u4s[408] | csL[384] | sA[2][192]
#define OFF_WL 0
#define OFF_PHIL 1568
#define OFF_U4S (OFF_PHIL + 150528)
#define OFF_CSL (OFF_U4S + 1632)
#define OFF_SA (OFF_CSL + 1536)
#define SMEM_BYTES (OFF_SA + 1536)

extern __shared__ char smem[];

__global__ __launch_bounds__(768, 1) void fused_kernel(
    const float* __restrict__ x, const float* __restrict__ y,
    const ushort* __restrict__ w1b, const ushort* __restrict__ w2b,
    const float* __restrict__ cvecs, const float* __restrict__ u4,
    const float* __restrict__ u3, const float* __restrict__ Kc,
    float* __restrict__ out) {
  const int b = blockIdx.x;
  float* Wl = (float*)(smem + OFF_WL);
  char* phiB = smem + OFF_PHIL;
  float* u4s = (float*)(smem + OFF_U4S);
  float* csL = (float*)(smem + OFF_CSL);
  float* sA = (float*)(smem + OFF_SA);    // [2][192]
  const int tid = threadIdx.x;
  for (int i = tid; i < 408; i += 768) u4s[i] = (i < LTOT) ? u4[i] : 0.f;
  for (int i = tid; i < 384; i += 768) csL[i] = cvecs[i];

  const int w = tid >> 6, lane = tid & 63;
  const int cw = w % 6, lg = w / 6;       // wave owns c-tile cw (32 ch), l-group lg
  const int cbase = cw * 32;
  const int cl32 = lane & 31, hi = lane >> 5;
  const int c = cbase + cl32;             // this lane's channel (epi/B-frag)

  bf16x8 bfr[12];                         // current half's B-frags (K=192 = 12x16)
#pragma unroll
  for (int kk = 0; kk < 12; kk++)
    bfr[kk] = *(const bf16x8*)(w1b + (size_t)c * CDIM + kk * 16 + hi * 8);

  const float4* xb4 = (const float4*)(x + (size_t)b * NTOK * CDIM);
  const float4* yb4 = (const float4*)(y + (size_t)b * NTOK * CDIM);
  float4 pfA[6], pfB[7];
  float sp = 0.f;

  // chunkA = rows 0..95 (4608 f4, exact); chunkB = rows 96..195 (4800 f4, mask)
  auto loadA = [&](const float4* s4) {
#pragma unroll
    for (int p = 0; p < 6; p++) pfA[p] = s4[p * 768 + tid];
  };
  auto loadB = [&](const float4* s4) {
#pragma unroll
    for (int p = 0; p < 7; p++) {
      const int fi = p * 768 + tid;
      pfB[p] = (fi < 4800) ? s4[4608 + fi] : float4{0.f, 0.f, 0.f, 0.f};
    }
  };
  auto stageA = [&](int h) {
#pragma unroll
    for (int p = 0; p < 6; p++) {
      const int fi = p * 768 + tid;
      const int l = h * NTOK + fi / 48, c4 = fi % 48;
      uint2 wv;
      wv.x = pk2(pfA[p].x, pfA[p].y);
      wv.y = pk2(pfA[p].z, pfA[p].w);
      uint addr = (uint)(l * 384 + c4 * 8) ^ (uint)((l & 7) << 4);
      *(uint2*)(phiB + addr) = wv;
    }
  };
  auto stageB = [&](int h) {
#pragma unroll
    for (int p = 0; p < 7; p++) {
      const int fi = p * 768 + tid;
      if (fi < 4800) {
        const int l = h * NTOK + 96 + fi / 48, c4 = fi % 48;
        uint2 wv;
        wv.x = pk2(pfB[p].x, pfB[p].y);
        wv.y = pk2(pfB[p].z, pfB[p].w);
        uint addr = (uint)(l * 384 + c4 * 8) ^ (uint)((l & 7) << 4);
        *(uint2*)(phiB + addr) = wv;
      }
    }
  };

  // one 32x32 tile: MFMA into acc (A from phiL rows l0..l0+31 of half h)
  auto tileMFMA = [&](int h, int l0) -> f32x16 {
    f32x16 acc;
#pragma unroll
    for (int e = 0; e < 16; e++) acc[e] = 0.f;
    const int l = h * NTOK + l0 + cl32;
    const uint swz = (uint)((l & 7) << 4);
    __builtin_amdgcn_s_setprio(1);
#pragma unroll
    for (int kk = 0; kk < 12; kk++) {
      uint ad = (uint)(l * 384 + kk * 32 + hi * 16) ^ swz;
      bf16x8 af = *(const bf16x8*)(phiB + ad);
      acc = __builtin_amdgcn_mfma_f32_32x32x16_bf16(af, bfr[kk], acc, 0, 0, 0);
    }
    __builtin_amdgcn_s_setprio(0);
    return acc;
  };
  // epi: relu+bias -> phi overwrites A rows; s partial. ovl: only rows >= 192.
  auto tileEPI = [&](int h, int l0, const f32x16& acc, float csr, bool ovl) {
#pragma unroll
    for (int e = 0; e < 16; e++) {
      const int rl = (e & 3) + 8 * (e >> 2) + 4 * hi;
      const int row = l0 + rl;
      if (!ovl || row >= 192) {
        const float v = fmaxf(acc[e] + csr, 0.f);
        const int l = h * NTOK + row;
        uint addr = (uint)(l * 384 + c * 2) ^ (uint)((l & 7) << 4);
        *(ushort*)(phiB + addr) = f2bf(v);
        sp += u4s[l] * v;
      }
    }
  };
  auto chunkCompute = [&](int h, int cb, float csr) {
    // cb=0: tiles {0,32,64}; cb=1: tiles {96,128,160,164(ovl)}
    const int l0s[2][4] = {{0, 32, 64, -1}, {96, 128, 160, 164}};
    const int nt = cb ? 4 : 3;
    f32x16 a0, a1;
    const int t0 = lg, t1 = lg + 2;
    if (t0 < nt) a0 = tileMFMA(h, l0s[cb][t0]);
    if (t1 < nt) a1 = tileMFMA(h, l0s[cb][t1]);
    barL();                               // all A reads drained before overwrite
    if (t0 < nt) tileEPI(h, l0s[cb][t0], a0, csr, cb && l0s[cb][t0] == 164);
    if (t1 < nt) tileEPI(h, l0s[cb][t1], a1, csr, cb && l0s[cb][t1] == 164);
  };

  loadA(xb4);
  loadB(xb4);
  stageA(0);
  loadA(yb4);                             // y chunkA issued here...
  __builtin_amdgcn_sched_barrier(0);      // ...and PINNED here (no sinking)
  barL();
  const float csr0 = csL[c], csr1 = csL[CDIM + c];
  chunkCompute(0, 0, csr0);
  stageB(0);
  loadB(yb4);                             // y chunkB issued here...
  __builtin_amdgcn_sched_barrier(0);      // ...pinned
  barL();
  chunkCompute(0, 1, csr0);
#pragma unroll
  for (int kk = 0; kk < 12; kk++)         // switch to half-1 weights (L2-hot)
    bfr[kk] = *(const bf16x8*)(w2b + (size_t)c * CDIM + kk * 16 + hi * 8);
  __builtin_amdgcn_sched_barrier(0);      // pin weight reload issue
  stageA(1);
  barL();
  chunkCompute(1, 0, csr1);
  stageB(1);
  barL();
  chunkCompute(1, 1, csr1);

  // s reduction: lane holds column c over its rows; fold hi via xor 32
  sp += __shfl_xor(sp, 32);
  if (hi == 0) sA[lg * CDIM + c] = sp;
  barL();
  for (int i = tid; i < CDIM; i += 768) sA[i] = u3[i] + sA[i] + sA[CDIM + i];
  barL();

  // W phase: 16 rows x 4 kgrp per wave (bank-balanced b128 reads), W -> Wl
  {
    const float Kv = Kc[0];
    const int lrow = lane & 15, kgrp = lane >> 4;
#pragma unroll
    for (int p = 0; p < 3; p++) {
      const int row = p * 192 + w * 16 + lrow;
      float acc = 0.f;
      if (row < LTOT) {
#pragma unroll
        for (int kk = 0; kk < 6; kk++) {
          const int c0 = kk * 32 + kgrp * 8;
          uint addr = (uint)(row * 384 + c0 * 2) ^ (uint)((row & 7) << 4);
          const uint4 pv = *(const uint4*)(phiB + addr);
          const float4 cfa = *(const float4*)&sA[c0];
          const float4 cfb = *(const float4*)&sA[c0 + 4];
          acc += cfa.x * bf2f((ushort)pv.x) + cfa.y * bf2f((ushort)(pv.x >> 16))
               + cfa.z * bf2f((ushort)pv.y) + cfa.w * bf2f((ushort)(pv.y >> 16))
               + cfb.x * bf2f((ushort)pv.z) + cfb.y * bf2f((ushort)(pv.z >> 16))
               + cfb.z * bf2f((ushort)pv.w) + cfb.w * bf2f((ushort)(pv.w >> 16));
        }
      }
      acc += __shfl_xor(acc, 16);
      acc += __shfl_xor(acc, 32);
      if (kgrp == 0 && row < LTOT) Wl[row] = acc + Kv;
    }
  }
  barL();  // Wl visible; phiL reads done -> tiles may overwrite

  // out phase: barrier-free, 1-slab register pipeline. Wave owns c-strip
  // [w*16, w*16+16); private slab [16][68] f32 over dead phiL; 4 slabs of 64 n.
  {
    float* tf = (float*)(phiB + w * 4352);    // 16*68*4 = 4352 B per wave
    const int cb16 = w * 16;
    const float* xb = x + (size_t)b * NTOK * CDIM;
    const float* yb = y + (size_t)b * NTOK * CDIM;
    const int nrow = lane >> 2, cq = lane & 3;     // combine mapping
    const int scl = lane >> 2, sq = lane & 3;      // store mapping
    float4 px[4], py[4];
#pragma unroll
    for (int i2 = 0; i2 < 4; i2++) {               // prefetch slab 0 (n<196 all)
      const int n = i2 * 16 + nrow;
      const size_t xi = (size_t)n * CDIM + cb16 + cq * 4;
      px[i2] = *(const float4*)&xb[xi];
      py[i2] = *(const float4*)&yb[xi];
    }
    __builtin_amdgcn_sched_barrier(0);
    for (int s0 = 0; s0 < 4; s0++) {
      const int n0 = s0 * 64;
      // combine current slab (first px use waits on its loads)
#pragma unroll
      for (int i2 = 0; i2 < 4; i2++) {
        const int n = n0 + i2 * 16 + nrow;
        if (n < NTOK) {
          const float wx = Wl[n], wy = Wl[NTOK + n];
          const int dn = i2 * 16 + nrow;
          tf[(cq * 4 + 0) * 68 + dn] = px[i2].x * wx + py[i2].x * wy;
          tf[(cq * 4 + 1) * 68 + dn] = px[i2].y * wx + py[i2].y * wy;
          tf[(cq * 4 + 2) * 68 + dn] = px[i2].z * wx + py[i2].z * wy;
          tf[(cq * 4 + 3) * 68 + dn] = px[i2].w * wx + py[i2].w * wy;
        }
      }
      __builtin_amdgcn_sched_barrier(0);
      if (s0 < 3) {                        // issue next slab, in flight over stores
#pragma unroll
        for (int i2 = 0; i2 < 4; i2++) {
          const int n = n0 + 64 + i2 * 16 + nrow;
          if (n < NTOK) {
            const size_t xi = (size_t)n * CDIM + cb16 + cq * 4;
            px[i2] = *(const float4*)&xb[xi];
            py[i2] = *(const float4*)&yb[xi];
          } else {
            px[i2] = float4{0.f, 0.f, 0.f, 0.f};
            py[i2] = float4{0.f, 0.f, 0.f, 0.f};
          }
        }
        __builtin_amdgcn_sched_barrier(0);
      }
      asm volatile("s_waitcnt lgkmcnt(0)" ::: "memory");  // own slab writes done
#pragma unroll
      for (int i2 = 0; i2 < 4; i2++) {
        const int n = n0 + i2 * 16 + sq * 4;
        if (n < NTOK) {
          const float4 o = *(const float4*)&tf[scl * 68 + (n - n0)];
          *(float4*)&out[((size_t)b * CDIM + cb16 + scl) * NTOK + n] = o;
        }
      }
    }
  }
}

extern "C" void kernel_launch(void* const* d_in, const int* in_sizes, int n_in,
                              void* d_out, int out_size, void* d_ws, size_t ws_size,
                              hipStream_t stream) {
  const float* x   = (const float*)d_in[0];
  const float* y   = (const float*)d_in[1];
  const float* w1  = (const float*)d_in[2];
  const float* b1  = (const float*)d_in[3];
  const float* g1  = (const float*)d_in[4];
  const float* be1 = (const float*)d_in[5];
  const float* m1  = (const float*)d_in[6];
  const float* v1  = (const float*)d_in[7];
  const float* w2  = (const float*)d_in[8];
  const float* b2  = (const float*)d_in[9];
  const float* g2  = (const float*)d_in[10];
  const float* be2 = (const float*)d_in[11];
  const float* m2  = (const float*)d_in[12];
  const float* v2  = (const float*)d_in[13];
  const float* w3  = (const float*)d_in[14];
  const float* b3  = (const float*)d_in[15];
  const float* w4  = (const float*)d_in[16];
  const float* b4  = (const float*)d_in[17];
  const float* w5  = (const float*)d_in[18];
  const float* b5  = (const float*)d_in[19];
  float* out = (float*)d_out;

  char* ws = (char*)d_ws;
  ushort* w1b  = (ushort*)ws;             // 73728 B
  ushort* w2b  = (ushort*)(ws + 73728);   // 73728 B
  float* fbase = (float*)(ws + 147456);
  float* u3    = fbase;                   // 192
  float* u4    = fbase + 192;             // 392
  float* cvecs = fbase + 584;             // 384 (c1|c2)
  float* Kc    = fbase + 968;             // 1

  prep_kernel<<<211, 256, 0, stream>>>(w1, b1, g1, be1, m1, v1,
                                       w2, b2, g2, be2, m2, v2,
                                       w3, b3, w4, b4, w5, b5,
                                       w1b, w2b, u3, u4, cvecs, Kc);
  fused_kernel<<<256, 768, SMEM_BYTES, stream>>>(x, y, w1b, w2b, cvecs, u4,
                                                 u3, Kc, out);
}